// Round 10
// baseline (290.438 us; speedup 1.0000x reference)
//
#include <hip/hip_runtime.h>

#define WD   192
#define HD   192
#define HWD  (WD*HD)
#define NCH  64
#define NOUT 64
#define NK   5
#define BAND 12            // rows per block; grid = 16 bands x 16 imgs = 256 = 1/CU
#define SLOTS 6            // ring: reads r-1..r+2, writes r+3,r+4 (distinct mod 6)
#define COLS 194           // 1 zero-pad + 192 + 1 zero-pad
#define ROWB 128           // bytes per pixel entry (64 ch bf16), XOR-swizzled

typedef __attribute__((ext_vector_type(8))) short short8;
typedef __attribute__((ext_vector_type(4))) float f32x4;

__device__ inline ushort f2bf(float f) {
  union { float f; unsigned u; } xx; xx.f = f;
  unsigned u = xx.u;
  return (ushort)((u + 0x7FFFu + ((u >> 16) & 1u)) >> 16);   // RNE
}

// Swizzled LDS byte offset: row-stride 128 B, XOR (pix&7) into bits 4..6.
// Involution on BOTH write and read -> bijective, conflict-free b128.
// NOT linear in cbyte across bits 4..6 -> compute per cbyte value.
__device__ inline int ldso(int slot, int pix, int cbyte) {
  int byte = (slot * COLS + pix) * ROWB + cbyte;
  return byte ^ ((pix & 7) << 4);
}

// taps[5..9] = dr ; taps[10..14] = dc   (runtime rot read on-device)
__global__ void prep_taps_k(const int* __restrict__ rot, int* __restrict__ taps) {
  const int ring_r[8] = {0,0,1,2,2,2,1,0};
  const int ring_c[8] = {1,2,2,2,1,0,0,0};
  int off = ((rot[0] % 8) + 8) % 8;   // step = 8/kernel_rot = 1
  for (int k = 0; k < 4; ++k) {
    int p = (2*k + off) & 7;
    taps[k] = 0; taps[5 + k] = ring_r[p] - 1; taps[10 + k] = ring_c[p] - 1;
  }
  taps[4] = 0; taps[9] = 0; taps[14] = 0;   // center tap
}

__device__ inline unsigned s6(int gr) { return (unsigned)(gr + 6) % 6u; }

// Raw barrier WITHOUT the __syncthreads vmcnt(0) drain: only LDS ops fenced.
// Prefetch loads and output stores stay in flight across it (T3/T4 pattern).
__device__ inline void lds_barrier() {
  __builtin_amdgcn_sched_barrier(0);
  asm volatile("s_waitcnt lgkmcnt(0)" ::: "memory");
  __builtin_amdgcn_sched_barrier(0);
  __builtin_amdgcn_s_barrier();
  __builtin_amdgcn_sched_barrier(0);
}

__global__ __launch_bounds__(512, 2) void rconv_ring_k(
    const float* __restrict__ x, const float* __restrict__ w,
    const int* __restrict__ taps, float* __restrict__ out) {
  __shared__ ushort lds[SLOTS * COLS * (ROWB / 2)];   // 148,992 B (1 block/CU)
  char* ldsb = (char*)lds;

  const int tid  = threadIdx.x;
  const int lane = tid & 63;
  const int wv   = tid >> 6;        // 0..7
  const int l15  = lane & 15;
  const int g    = lane >> 4;       // 0..3
  const int r0   = blockIdx.x * BAND;
  const int n    = blockIdx.y;
  const int o0w  = (wv & 1) * 32;   // o-half owned by this wave (32 o)
  const int wq   = wv >> 1;         // pixel quarter (48 pix)

  int dr[NK], dc[NK];
  #pragma unroll
  for (int k = 0; k < NK; ++k) { dr[k] = taps[5 + k]; dc[k] = taps[10 + k]; }

  // A fragments (80 VGPR): a[ot][kc][k], elem j = W[o0w+ot*16+l15][kc*32+g*8+j][k]
  // (same (g,j)->c map as B fragments => correct for any HW canonical k-layout)
  short8 a[2][2][NK];
  #pragma unroll
  for (int ot = 0; ot < 2; ++ot)
    #pragma unroll
    for (int kc = 0; kc < 2; ++kc)
      #pragma unroll
      for (int k = 0; k < NK; ++k) {
        short8 t;
        #pragma unroll
        for (int j = 0; j < 8; ++j)
          t[j] = (short)f2bf(w[(size_t)(o0w + ot*16 + l15) * (NCH*NK)
                               + (kc*32 + g*8 + j) * NK + k]);
        a[ot][kc][k] = t;
      }

  // staging: wave wv owns channels [wv*8, wv*8+8)
  const float* xn = x + ((size_t)n * NCH + wv * 8) * HWD;

  auto stage_load = [&](int gr, float v[3][8]) {
    bool vr = (gr >= 0) && (gr < HD);
    if (vr) {
      const float* xr = xn + (size_t)gr * WD;
      #pragma unroll
      for (int i = 0; i < 3; ++i)
        #pragma unroll
        for (int j = 0; j < 8; ++j)
          v[i][j] = xr[(size_t)j * HWD + i * 64 + lane];
    } else {
      #pragma unroll
      for (int i = 0; i < 3; ++i)
        #pragma unroll
        for (int j = 0; j < 8; ++j) v[i][j] = 0.f;
    }
  };
  auto cvt_row = [&](const float v[3][8], short8 c[3]) {
    #pragma unroll
    for (int i = 0; i < 3; ++i) {
      short8 t;
      #pragma unroll
      for (int j = 0; j < 8; ++j) t[j] = (short)f2bf(v[i][j]);
      c[i] = t;
    }
  };
  auto stage_write_bf = [&](int gr, const short8 c[3]) {
    int s = s6(gr);
    #pragma unroll
    for (int i = 0; i < 3; ++i)
      *reinterpret_cast<short8*>(ldsb + ldso(s, 1 + i * 64 + lane, wv * 16)) = c[i];
    if (lane < 2) {   // zero the left/right pad pixels (cols 0 and 193)
      short8 z = (short8){0,0,0,0,0,0,0,0};
      *reinterpret_cast<short8*>(ldsb + ldso(s, lane * (COLS - 1), wv * 16)) = z;
    }
  };

  // compute row r from slots (r-1,r,r+1): 32o x 48pix per wave, 2 MFMAs/b128
  auto compute_row = [&](int r, f32x4 acc[3][2]) {
    int bo0[NK], bo1[NK];
    #pragma unroll
    for (int k = 0; k < NK; ++k) {
      int pix = wq * 48 + dc[k] + 1 + l15;
      bo0[k] = ldso(s6(r + dr[k]), pix, g * 16);
      bo1[k] = ldso(s6(r + dr[k]), pix, g * 16 + 64);   // NOT bo0+64 (swizzle)
    }
    #pragma unroll
    for (int t = 0; t < 3; ++t) {
      acc[t][0] = (f32x4){0.f, 0.f, 0.f, 0.f};
      acc[t][1] = (f32x4){0.f, 0.f, 0.f, 0.f};
    }
    __builtin_amdgcn_s_setprio(1);
    #pragma unroll
    for (int t = 0; t < 3; ++t)
      #pragma unroll
      for (int k = 0; k < NK; ++k) {
        // +t*16*ROWB only touches bits >= 11 -> linear add is swizzle-safe
        short8 b0 = *reinterpret_cast<const short8*>(ldsb + bo0[k] + t * 16 * ROWB);
        short8 b1 = *reinterpret_cast<const short8*>(ldsb + bo1[k] + t * 16 * ROWB);
        acc[t][0] = __builtin_amdgcn_mfma_f32_16x16x32_bf16(a[0][0][k], b0, acc[t][0], 0, 0, 0);
        acc[t][1] = __builtin_amdgcn_mfma_f32_16x16x32_bf16(a[1][0][k], b0, acc[t][1], 0, 0, 0);
        acc[t][0] = __builtin_amdgcn_mfma_f32_16x16x32_bf16(a[0][1][k], b1, acc[t][0], 0, 0, 0);
        acc[t][1] = __builtin_amdgcn_mfma_f32_16x16x32_bf16(a[1][1][k], b1, acc[t][1], 0, 0, 0);
      }
    __builtin_amdgcn_s_setprio(0);
  };
  auto store_row = [&](int r, const f32x4 acc[3][2]) {
    size_t ob = ((size_t)(n * NOUT + o0w + 4 * g) * HD + r) * WD + wq * 48 + l15;
    #pragma unroll
    for (int t = 0; t < 3; ++t)
      #pragma unroll
      for (int ot = 0; ot < 2; ++ot)
        #pragma unroll
        for (int q = 0; q < 4; ++q)
          out[ob + (size_t)(ot * 16 + q) * HWD + t * 16] = acc[t][ot][q];
  };

  float vA0[3][8], vA1[3][8], vB0[3][8], vB1[3][8];
  f32x4 accA[3][2], accB[3][2];

  // prologue: stage rows r0-1..r0+2; leave loads of rows r0+3,r0+4 in flight (vA)
  {
    short8 c[3];
    stage_load(r0 - 1, vA0); stage_load(r0, vA1);
    cvt_row(vA0, c); stage_write_bf(r0 - 1, c);
    cvt_row(vA1, c); stage_write_bf(r0,     c);
    stage_load(r0 + 1, vA0); stage_load(r0 + 2, vA1);
    cvt_row(vA0, c); stage_write_bf(r0 + 1, c);
    cvt_row(vA1, c); stage_write_bf(r0 + 2, c);
    stage_load(r0 + 3, vA0); stage_load(r0 + 4, vA1);
  }
  __syncthreads();

  // 2-row phase (src holds rows r+3,r+4 loaded last phase; dst gets r+5,r+6):
  //  1. cvt src (vmcnt waits ONLY 1-phase-old loads -> free; frees fp32 regs)
  //  2. issue next loads (2-phase-deep pipeline)
  //  3. compute r, r+1 (independent accA/accB; 120 MFMA cluster)
  //  4. ds_write rows r+3,r+4 from bf16 regs (NO vm dependency)
  //  5. one lgkm-only barrier  6. stores of both rows drain under next phase
  auto phase = [&](int r, float (&s0)[3][8], float (&s1)[3][8],
                   float (&d0)[3][8], float (&d1)[3][8]) {
    const bool gw = (r + 3 <= r0 + BAND);   // write/cvt rows r+3,r+4 needed?
    const bool gl = (r + 5 <= r0 + BAND);   // load rows r+5,r+6 needed?
    short8 c0[3], c1[3];
    if (gw) { cvt_row(s0, c0); cvt_row(s1, c1); }
    if (gl) { stage_load(r + 5, d0); stage_load(r + 6, d1); }
    compute_row(r,     accA);
    compute_row(r + 1, accB);
    if (gw) { stage_write_bf(r + 3, c0); stage_write_bf(r + 4, c1); }
    lds_barrier();
    store_row(r,     accA);
    store_row(r + 1, accB);
  };

  #pragma unroll 1
  for (int ii = 0; ii < BAND / 4; ++ii) {
    int r = r0 + 4 * ii;
    phase(r,     vA0, vA1, vB0, vB1);
    phase(r + 2, vB0, vB1, vA0, vA1);
  }
}

extern "C" void kernel_launch(void* const* d_in, const int* in_sizes, int n_in,
                              void* d_out, int out_size, void* d_ws, size_t ws_size,
                              hipStream_t stream) {
  const float* x = (const float*)d_in[0];
  const float* w = (const float*)d_in[1];
  const int* rot = (const int*)d_in[2];
  float* out     = (float*)d_out;
  int* taps      = (int*)d_ws;

  const int nbatch = in_sizes[0] / (NCH * HWD);   // 16

  hipLaunchKernelGGL(prep_taps_k, dim3(1), dim3(1), 0, stream, rot, taps);
  hipLaunchKernelGGL(rconv_ring_k, dim3(HD / BAND, nbatch), dim3(512), 0, stream,
                     x, w, taps, out);
}

// Round 11
// 85.385 us; speedup vs baseline: 3.4015x; 3.4015x over previous
//
#include <hip/hip_runtime.h>

#define WD   192
#define HD   192
#define HWD  (WD*HD)
#define NCH  64
#define NOUT 64
#define NK   5
#define BAND 12            // rows per block; grid = 16 bands x 16 imgs = 256 = 1/CU
#define COLS 194           // 1 zero-pad + 192 + 1 zero-pad
#define ROWB 128           // bytes per pixel entry (64 ch bf16), XOR-swizzled

typedef __attribute__((ext_vector_type(8))) short short8;
typedef __attribute__((ext_vector_type(4))) short short4v;
typedef __attribute__((ext_vector_type(4))) float f32x4;

__device__ inline ushort f2bf(float f) {
  union { float f; unsigned u; } xx; xx.f = f;
  unsigned u = xx.u;
  return (ushort)((u + 0x7FFFu + ((u >> 16) & 1u)) >> 16);   // RNE
}

// Swizzled LDS byte offset: row-stride 128 B, XOR (pix&7) into bits 4..6.
// Involution on BOTH write and read -> bijective, conflict-free b128.
// NOT linear in cbyte across bits 4..6 -> compute per cbyte value.
__device__ inline int ldso(int slot, int pix, int cbyte) {
  int byte = (slot * COLS + pix) * ROWB + cbyte;
  return byte ^ ((pix & 7) << 4);
}

// taps[5..9] = dr ; taps[10..14] = dc   (runtime rot read on-device)
__global__ void prep_taps_k(const int* __restrict__ rot, int* __restrict__ taps) {
  const int ring_r[8] = {0,0,1,2,2,2,1,0};
  const int ring_c[8] = {1,2,2,2,1,0,0,0};
  int off = ((rot[0] % 8) + 8) % 8;   // step = 8/kernel_rot = 1
  for (int k = 0; k < 4; ++k) {
    int p = (2*k + off) & 7;
    taps[k] = 0; taps[5 + k] = ring_r[p] - 1; taps[10 + k] = ring_c[p] - 1;
  }
  taps[4] = 0; taps[9] = 0; taps[14] = 0;   // center tap
}

// Raw barrier WITHOUT the __syncthreads vmcnt(0) drain: only LDS ops fenced.
// Prefetch loads and output stores stay in flight across it (T3/T4 pattern).
__device__ inline void lds_barrier() {
  __builtin_amdgcn_sched_barrier(0);
  asm volatile("s_waitcnt lgkmcnt(0)" ::: "memory");
  __builtin_amdgcn_sched_barrier(0);
  __builtin_amdgcn_s_barrier();
  __builtin_amdgcn_sched_barrier(0);
}

__global__ __launch_bounds__(1024, 4) void rconv_ring_k(
    const float* __restrict__ x, const float* __restrict__ w,
    const int* __restrict__ taps, float* __restrict__ out) {
  __shared__ ushort lds[4 * COLS * (ROWB / 2)];   // 99,328 B; 1024-thr block (16 waves)
  char* ldsb = (char*)lds;

  const int tid  = threadIdx.x;
  const int lane = tid & 63;
  const int wv   = tid >> 6;        // 0..15
  const int l15  = lane & 15;
  const int g    = lane >> 4;       // 0..3
  const int r0   = blockIdx.x * BAND;
  const int n    = blockIdx.y;
  const int o0w  = (wv & 3) * 16;   // o-tile owned by this wave (16 o)
  const int wq   = wv >> 2;         // pixel quarter (48 pix)

  int dr[NK], dc[NK];
  #pragma unroll
  for (int k = 0; k < NK; ++k) { dr[k] = taps[5 + k]; dc[k] = taps[10 + k]; }

  // A fragments (40 VGPR): a[kc][k], elem j = W[o0w+l15][kc*32+g*8+j][k]
  // (same (g,j)->c map as B fragments => correct for any HW canonical k-layout)
  short8 a[2][NK];
  #pragma unroll
  for (int kc = 0; kc < 2; ++kc)
    #pragma unroll
    for (int k = 0; k < NK; ++k) {
      short8 t;
      #pragma unroll
      for (int j = 0; j < 8; ++j)
        t[j] = (short)f2bf(w[(size_t)(o0w + l15) * (NCH*NK)
                             + (kc*32 + g*8 + j) * NK + k]);
      a[kc][k] = t;
    }

  // staging: wave wv owns channels [wv*4, wv*4+4)  (16 waves x 4 ch = 64)
  const float* xn = x + ((size_t)n * NCH + wv * 4) * HWD;

  auto stage_load = [&](int gr, float v[3][4]) {
    bool vr = (gr >= 0) && (gr < HD);
    if (vr) {
      const float* xr = xn + (size_t)gr * WD;
      #pragma unroll
      for (int i = 0; i < 3; ++i)
        #pragma unroll
        for (int j = 0; j < 4; ++j)
          v[i][j] = xr[(size_t)j * HWD + i * 64 + lane];
    } else {
      #pragma unroll
      for (int i = 0; i < 3; ++i)
        #pragma unroll
        for (int j = 0; j < 4; ++j) v[i][j] = 0.f;
    }
  };
  auto stage_write = [&](int gr, const float v[3][4]) {
    int s = gr & 3;
    #pragma unroll
    for (int i = 0; i < 3; ++i) {
      short4v t;
      #pragma unroll
      for (int j = 0; j < 4; ++j) t[j] = (short)f2bf(v[i][j]);
      *reinterpret_cast<short4v*>(ldsb + ldso(s, 1 + i * 64 + lane, wv * 8)) = t;
    }
    if (lane < 2) {   // zero the left/right pad pixels (cols 0 and 193)
      short4v z = (short4v){0,0,0,0};
      *reinterpret_cast<short4v*>(ldsb + ldso(s, lane * (COLS - 1), wv * 8)) = z;
    }
  };

  // compute row r from slots (r-1,r,r+1): 16o x 48pix per wave
  f32x4 acc[3];
  auto compute_row = [&](int r) {
    int bo0[NK], bo1[NK];
    #pragma unroll
    for (int k = 0; k < NK; ++k) {
      int pix = wq * 48 + dc[k] + 1 + l15;
      bo0[k] = ldso((r + dr[k]) & 3, pix, g * 16);
      bo1[k] = ldso((r + dr[k]) & 3, pix, g * 16 + 64);   // NOT bo0+64 (swizzle)
    }
    #pragma unroll
    for (int t = 0; t < 3; ++t) acc[t] = (f32x4){0.f, 0.f, 0.f, 0.f};
    __builtin_amdgcn_s_setprio(1);
    #pragma unroll
    for (int t = 0; t < 3; ++t)
      #pragma unroll
      for (int k = 0; k < NK; ++k) {
        // +t*16*ROWB only touches bits >= 11 -> linear add is swizzle-safe
        short8 b0 = *reinterpret_cast<const short8*>(ldsb + bo0[k] + t * 16 * ROWB);
        short8 b1 = *reinterpret_cast<const short8*>(ldsb + bo1[k] + t * 16 * ROWB);
        acc[t] = __builtin_amdgcn_mfma_f32_16x16x32_bf16(a[0][k], b0, acc[t], 0, 0, 0);
        acc[t] = __builtin_amdgcn_mfma_f32_16x16x32_bf16(a[1][k], b1, acc[t], 0, 0, 0);
      }
    __builtin_amdgcn_s_setprio(0);
  };
  auto store_row = [&](int r) {
    size_t ob = ((size_t)(n * NOUT + o0w + 4 * g) * HD + r) * WD + wq * 48 + l15;
    #pragma unroll
    for (int t = 0; t < 3; ++t)
      #pragma unroll
      for (int q = 0; q < 4; ++q)
        out[ob + (size_t)q * HWD + t * 16] = acc[t][q];
  };

  float vA[3][4], vB[3][4];

  // prologue: rows r0-1..r0+1 staged; loads for r0+2 in flight (vA)
  stage_load(r0 - 1, vA); stage_write(r0 - 1, vA);
  stage_load(r0,     vA); stage_write(r0,     vA);
  stage_load(r0 + 1, vA); stage_write(r0 + 1, vA);
  stage_load(r0 + 2, vA);
  lds_barrier();

  // R6 schedule (proven): per row, ONE lgkm-only barrier (4-slot ring:
  // write slot (r+2)&3 disjoint from read slots (r-1,r,r+1)&3).
  //   loads(r+3, other buf) -> compute r -> stage_write(r+2) [vmcnt wait is
  //   COUNTED: ~24 younger ops (prev stores + this phase's loads)] ->
  //   barrier -> stores r drain under next phase.
  #pragma unroll 1
  for (int i = 0; i < BAND / 2; ++i) {
    int r = r0 + 2 * i;
    {
      if (r + 3 <= r0 + BAND) stage_load(r + 3, vB);
      compute_row(r);
      stage_write(r + 2, vA);            // r+2 <= r0+BAND always here
      lds_barrier();
      store_row(r);
    }
    {
      int r1 = r + 1;
      if (r1 + 3 <= r0 + BAND) stage_load(r1 + 3, vA);
      compute_row(r1);
      if (r1 + 2 <= r0 + BAND) stage_write(r1 + 2, vB);
      lds_barrier();
      store_row(r1);
    }
  }
}

extern "C" void kernel_launch(void* const* d_in, const int* in_sizes, int n_in,
                              void* d_out, int out_size, void* d_ws, size_t ws_size,
                              hipStream_t stream) {
  const float* x = (const float*)d_in[0];
  const float* w = (const float*)d_in[1];
  const int* rot = (const int*)d_in[2];
  float* out     = (float*)d_out;
  int* taps      = (int*)d_ws;

  const int nbatch = in_sizes[0] / (NCH * HWD);   // 16

  hipLaunchKernelGGL(prep_taps_k, dim3(1), dim3(1), 0, stream, rot, taps);
  hipLaunchKernelGGL(rconv_ring_k, dim3(HD / BAND, nbatch), dim3(1024), 0, stream,
                     x, w, taps, out);
}